// Round 2
// baseline (263.668 us; speedup 1.0000x reference)
//
#include <hip/hip_runtime.h>

// WindowEmbedding forward: out[b,t, w*D+d] = (t-w>=0) ? in[b, t-w, d] : 0
// B=16, T=2048, D=256, W=7.
//
// Round 8: per-WAVE linear store streams. Evidence: scatter (r6) and
// block-contiguous gather (r7) both land at ~105us kernel-part (2.5 TB/s),
// while the harness fill hits 6.2-6.4 TB/s at ~3 waves/CU occupancy. The
// fill's distinguishing feature is that each wave issues long runs of
// address-ascending contiguous stores; both our kernels issued 1KiB stores
// at ~7KiB per-wave stride. This round: one wave owns G=8 CONSECUTIVE
// output rows = one 56KiB contiguous span, stored in strictly ascending
// order (i ascending, w ascending -> addr ascending). The 14 input rows it
// needs are front-loaded into registers (56 VGPRs), so the store burst is
// uninterrupted. Read amp 14/8 = 1.75x -> ~56MB fetch (~+4us equiv), a
// cheap trade for a fill-shaped write stream.
//
// 4096 waves total (4/SIMD across 1024 SIMDs); the fill proves streaming
// stores saturate at far lower occupancy. Batch-start waves (t0==0, 16 of
// 4096) zero v[0..5] instead of loading; no other divergence anywhere.

typedef float vf4 __attribute__((ext_vector_type(4)));

constexpr int B    = 16;
constexpr int T    = 2048;
constexpr int D    = 256;
constexpr int W    = 7;
constexpr int D4   = D / 4;         // 64 vec4 per (row, slot) segment = 1 wave-load
constexpr int ROW4 = W * D4;        // 448 vec4 per output row
constexpr int G    = 8;             // consecutive rows per wave (divides T)
constexpr int NLD  = G + W - 1;     // 14 input rows feeding G output rows
constexpr int NROW = B * T;         // 32768 rows
constexpr int NWAVE = NROW / G;     // 4096 waves
constexpr int NBLK  = NWAVE / 4;    // 1024 blocks of 256 threads

__global__ __launch_bounds__(256) void window_waverow_kernel(
    const vf4* __restrict__ in, vf4* __restrict__ out) {
  const int wid  = (blockIdx.x << 2) | (threadIdx.x >> 6);  // wave id [0, NWAVE)
  const int lane = threadIdx.x & 63;
  const int r0   = wid * G;            // first output row of this wave
  const int t0   = r0 & (T - 1);       // within-batch t of first row

  // v[j] holds input row (r0 - (W-1) + j), j = 0..NLD-1.
  vf4 v[NLD];
  if (t0 != 0) {
    // Bulk path (4080/4096 waves): all NLD source rows are in-batch.
    const vf4* src = in + (r0 - (W - 1)) * D4 + lane;
#pragma unroll
    for (int j = 0; j < NLD; ++j) v[j] = src[j * D4];
  } else {
    // Batch-start waves: rows r0-6..r0-1 don't exist -> zeros.
    const vf4 z = {0.f, 0.f, 0.f, 0.f};
#pragma unroll
    for (int j = 0; j < W - 1; ++j) v[j] = z;
    const vf4* src = in + r0 * D4 + lane;
#pragma unroll
    for (int j = 0; j < G; ++j) v[W - 1 + j] = src[j * D4];
  }

  // Store 56KiB in strictly ascending address order: row i, slot w ->
  // vec4 offset i*448 + w*64; source row r0+i-w -> v[i + (W-1) - w].
  vf4* dst = out + (size_t)r0 * ROW4 + lane;
#pragma unroll
  for (int i = 0; i < G; ++i) {
#pragma unroll
    for (int w = 0; w < W; ++w) {
      dst[i * ROW4 + w * D4] = v[i + (W - 1) - w];
    }
  }
}

extern "C" void kernel_launch(void* const* d_in, const int* in_sizes, int n_in,
                              void* d_out, int out_size, void* d_ws, size_t ws_size,
                              hipStream_t stream) {
  const vf4* in = (const vf4*)d_in[0];
  vf4* out = (vf4*)d_out;
  window_waverow_kernel<<<NBLK, 256, 0, stream>>>(in, out);
}

// Round 3
// 263.213 us; speedup vs baseline: 1.0017x; 1.0017x over previous
//
#include <hip/hip_runtime.h>

// WindowEmbedding forward: out[b,t, w*D+d] = (t-w>=0) ? in[b, t-w, d] : 0
// B=16, T=2048, D=256, W=7.
//
// Round 9: EXACTLY fill-shaped write stream. Evidence recap: three
// structurally different kernels (r6 scatter 254.1, r7 block-gather 259.8,
// r8 wave-gather 263.7) are within 4% -> the kernel part is likely small
// (~45-65us) and the total is dominated by harness fixed cost (fill ~151us
// + ~13 tiny reset dispatches + restore). The small regressions r7/r8 are
// consistent with their added read-amp / latency bubbles. This round is the
// decisive test: make the write side byte-for-byte the same walk as the
// 6.37 TB/s rocclr fill -- 256-thread blocks, each block owns one
// contiguous ascending 112KiB span, thread k stores vec4 at span[i*256+k]
// for i=0..27 (per-wave: 1KiB chunks at 4KiB stride, strictly ascending).
// Because 256 | 448*16 and 64 | 256, each wave-iteration covers exactly one
// aligned (row, w) segment: s = i*4+wave, row = s/7, w = s%7, source row =
// r0+row-w. Reads are 1KiB-aligned chunks from a 22KiB/block footprint
// reused ~7x intra-block (L1/L2-served); HBM fetch stays ~32-50MB.
// If this lands ~200us -> r6-r8 really were ~105us and per-wave store shape
// was the fix. If it lands ~254us -> kernel was already roofline; declare.

typedef float vf4 __attribute__((ext_vector_type(4)));

constexpr int B    = 16;
constexpr int T    = 2048;
constexpr int D    = 256;
constexpr int W    = 7;
constexpr int D4   = D / 4;           // 64 vec4 per (row,w) segment
constexpr int ROW4 = W * D4;          // 448 vec4 per output row
constexpr int RPB  = 16;              // rows per block (divides T)
constexpr int SPAN = RPB * ROW4;      // 7168 vec4 = 112 KiB per block
constexpr int THREADS = 256;
constexpr int ITER = SPAN / THREADS;  // 28 store instructions per thread
constexpr int NBLK = B * T / RPB;     // 2048 blocks

__global__ __launch_bounds__(THREADS) void window_linstore_kernel(
    const vf4* __restrict__ in, vf4* __restrict__ out) {
  const int tid  = threadIdx.x;
  const int lane = tid & 63;
  const int wv   = tid >> 6;          // wave 0..3
  const int r0   = blockIdx.x * RPB;  // first output row of this block
  const int t0   = r0 & (T - 1);

  const vf4* src = in + (size_t)r0 * D4 + lane;
  vf4* dst = out + (size_t)r0 * ROW4 + tid;

  if (t0 != 0) {
    // Bulk path (2032/2048 blocks): t0 >= 16 > 6, every source row valid.
#pragma unroll
    for (int i = 0; i < ITER; ++i) {
      unsigned s   = (unsigned)(i * 4 + wv);  // segment 0..111, wave-uniform
      unsigned row = s / 7u;                  // output row within block
      unsigned w   = s - row * 7u;            // window slot
      int sr = (int)row - (int)w;             // source row offset, may be <0
      vf4 v = src[sr * D4];
      dst[i * THREADS] = v;
    }
  } else {
    // Batch-start blocks (16 of 2048): rows 0..6 need zeros for w > row.
#pragma unroll
    for (int i = 0; i < ITER; ++i) {
      unsigned s   = (unsigned)(i * 4 + wv);
      unsigned row = s / 7u;
      unsigned w   = s - row * 7u;
      int sr = (int)row - (int)w;
      int srs = sr < 0 ? 0 : sr;              // safe address for masked lanes
      vf4 v = src[srs * D4];
      vf4 z = {0.f, 0.f, 0.f, 0.f};
      dst[i * THREADS] = (sr >= 0) ? v : z;   // wave-uniform select
    }
  }
}

extern "C" void kernel_launch(void* const* d_in, const int* in_sizes, int n_in,
                              void* d_out, int out_size, void* d_ws, size_t ws_size,
                              hipStream_t stream) {
  const vf4* in = (const vf4*)d_in[0];
  vf4* out = (vf4*)d_out;
  window_linstore_kernel<<<NBLK, THREADS, 0, stream>>>(in, out);
}

// Round 4
// 253.625 us; speedup vs baseline: 1.0396x; 1.0378x over previous
//
#include <hip/hip_runtime.h>
#include <hip/hip_bf16.h>

// WindowEmbedding forward: out[b,t, w*D+d] = (t-w>=0) ? in[b, t-w, d] : 0
// B=16, T=2048, D=256, W=7.
//
// Round 10: REVERSION to the round-6 input-centric scatter — the empirically
// best kernel (254.1us). Post-mortem of rounds 7-9: three structurally
// different alternatives (block-contiguous gather 259.8, wave-contiguous
// gather 263.7, exactly-fill-shaped write walk 263.2) all regressed. The
// write-stream-shape theory is falsified; the measured total is dominated by
// harness fixed cost (per-iteration 940MB poison fill at ~150us / 76% HBM
// peak + reset/restore dispatches), and among kernel structures the winner
// is the one with MINIMAL memory traffic and fewest load instructions:
// input-centric scatter reads each input byte exactly once from HBM
// (32 MiB), writes each output byte exactly once (224 MiB), 4 loads + <=28
// stores per thread. Every read-amplifying gather paid 6-9us for its extra
// L1/L2/HBM read traffic. Cache policy (NT vs plain) was A/B'd flat in the
// prior session; plain retained.

typedef float vf4 __attribute__((ext_vector_type(4)));

constexpr int B  = 16;
constexpr int T  = 2048;
constexpr int D  = 256;
constexpr int W  = 7;
constexpr int D4 = D / 4;              // 64 vec4 per (b,t,w) segment = 1 wave
constexpr int ROW4 = W * D4;           // 448 vec4 per output row
constexpr int CHUNK = 4;
constexpr int TOTAL4 = B * T * D4;     // 2,097,152 input vec4s
constexpr int S = TOTAL4 / CHUNK;      // 524,288 vec4 chunk stride
constexpr int SROW = S / D4;           // 8,192 rows per chunk stride (mult of T)
constexpr int SOUT = SROW * ROW4;      // output vec4 offset per chunk

__global__ __launch_bounds__(256) void window_scatter4_plain_kernel(
    const vf4* __restrict__ in, vf4* __restrict__ out) {
  int i0  = blockIdx.x * 256 + threadIdx.x;  // [0, S)
  int row = i0 >> 6;                         // b*T + t of chunk 0
  int dd  = i0 & 63;
  int t   = row & (T - 1);                   // identical for all 4 chunks

  vf4 v[CHUNK];
#pragma unroll
  for (int c = 0; c < CHUNK; ++c)
    v[c] = in[i0 + c * S];

  int base = row * ROW4 + dd;

#pragma unroll
  for (int w = 0; w < W; ++w) {
    if (t + w < T) {                         // wave-uniform
#pragma unroll
      for (int c = 0; c < CHUNK; ++c)
        out[base + c * SOUT + w * (ROW4 + D4)] = v[c];
    }
  }

  // edge zeros: slots (t, w) with w > t are never produced by any scatter.
  if (t < W - 1) {
    vf4 z = {0.f, 0.f, 0.f, 0.f};
    for (int w = t + 1; w < W; ++w) {
#pragma unroll
      for (int c = 0; c < CHUNK; ++c)
        out[base + c * SOUT + w * D4] = z;
    }
  }
}

extern "C" void kernel_launch(void* const* d_in, const int* in_sizes, int n_in,
                              void* d_out, int out_size, void* d_ws, size_t ws_size,
                              hipStream_t stream) {
  const vf4* in = (const vf4*)d_in[0];
  vf4* out = (vf4*)d_out;
  window_scatter4_plain_kernel<<<S / 256, 256, 0, stream>>>(in, out);
}